// Round 1
// baseline (98.468 us; speedup 1.0000x reference)
//
#include <hip/hip_runtime.h>
#include <stdint.h>

// Block-wise (128x128) fp8 e5m2 quantization with power-of-2 max-exponent scaling.
// Input:  x fp32 [8192, 8192]
// Output: d_out (f32 transport) = [8192*8192 quantized values] ++ [64*64 scales]
//
// One workgroup (512 threads) per 128x128 tile. Data held in registers
// (8 x float4 per thread) between the absmax pass and the quantize pass.

#define TS 128           // tile side
#define THREADS 512
#define NCOLS 8192
#define ROWS_PER_IT 16   // 512 threads / (128/4 float4 per row) = 16 rows per iteration
#define N_IT 8           // 128 rows / 16

// Exact round-to-nearest-even f32 -> e5m2 -> f32 (value domain).
// |v| < 8 in this problem (max scaled value in [2,4), rounds up to at most 4),
// so no overflow/saturation handling needed. Subnormal e5m2 (|v| < 2^-14)
// uses fixed quantum 2^-16. v == +-0 and f32 subnormals round to 0 correctly.
__device__ __forceinline__ float quant_e5m2(float v) {
    uint32_t b = __float_as_uint(v);
    int e = (int)((b >> 23) & 0xFFu) - 127;        // unbiased exponent (f32-subnormal -> -127, handled below)
    int ulp_e = (e >= -14) ? (e - 2) : -16;        // e5m2 ulp exponent
    float s  = __uint_as_float((uint32_t)(127 - ulp_e) << 23);  // 2^-ulp_e  (max 2^16, in range)
    float si = __uint_as_float((uint32_t)(127 + ulp_e) << 23);  // 2^+ulp_e
    return rintf(v * s) * si;                      // v_rndne_f32: RNE, all steps exact
}

__global__ __launch_bounds__(THREADS) void quantize_gm_kernel(
    const float* __restrict__ x,
    float* __restrict__ out_q,
    float* __restrict__ out_s,
    int nb_cols)
{
    const int tile = blockIdx.x;
    const int tr = tile / nb_cols;
    const int tc = tile - tr * nb_cols;
    const size_t base = (size_t)tr * TS * NCOLS + (size_t)tc * TS;

    const int t = threadIdx.x;
    const int row0 = t >> 5;          // 0..15: row within the 16-row stripe
    const int c4 = (t & 31) << 2;     // float column within tile row: 0,4,...,124

    // ---- load tile into registers (coalesced float4) ----
    const float4* __restrict__ xin = reinterpret_cast<const float4*>(x + base + c4);
    float4 v[N_IT];
#pragma unroll
    for (int i = 0; i < N_IT; ++i) {
        size_t r4 = (size_t)(i * ROWS_PER_IT + row0) * (NCOLS / 4);
        v[i] = xin[r4];
    }

    // ---- per-thread absmax ----
    float m = 0.0f;
#pragma unroll
    for (int i = 0; i < N_IT; ++i) {
        m = fmaxf(m, fmaxf(fmaxf(fabsf(v[i].x), fabsf(v[i].y)),
                           fmaxf(fabsf(v[i].z), fabsf(v[i].w))));
    }

    // ---- wave (64-lane) butterfly reduce ----
#pragma unroll
    for (int off = 32; off > 0; off >>= 1)
        m = fmaxf(m, __shfl_xor(m, off));

    // ---- cross-wave reduce via LDS ----
    __shared__ float smax[THREADS / 64];
    const int wave = t >> 6;
    if ((t & 63) == 0) smax[wave] = m;
    __syncthreads();
    float bm = smax[0];
#pragma unroll
    for (int w = 1; w < THREADS / 64; ++w) bm = fmaxf(bm, smax[w]);

    // ---- maxexp = floor(log2(absmax)) = exponent field (absmax normal, >0) ----
    const int maxexp = (int)((__float_as_uint(bm) >> 23) & 0xFFu) - 127;
    // factor = 2^(1 - maxexp); scale = 2^(maxexp - 1). Both exact powers of two.
    const float factor = __uint_as_float((uint32_t)(127 + 1 - maxexp) << 23);

    // ---- quantize + store (coalesced float4) ----
    float* __restrict__ oq = out_q + base + c4;
#pragma unroll
    for (int i = 0; i < N_IT; ++i) {
        size_t r = (size_t)(i * ROWS_PER_IT + row0) * NCOLS;
        float4 q;
        q.x = quant_e5m2(v[i].x * factor);
        q.y = quant_e5m2(v[i].y * factor);
        q.z = quant_e5m2(v[i].z * factor);
        q.w = quant_e5m2(v[i].w * factor);
        *reinterpret_cast<float4*>(oq + r) = q;
    }

    if (t == 0)
        out_s[tile] = __uint_as_float((uint32_t)(127 + maxexp - 1) << 23);
}

extern "C" void kernel_launch(void* const* d_in, const int* in_sizes, int n_in,
                              void* d_out, int out_size, void* d_ws, size_t ws_size,
                              hipStream_t stream) {
    const float* x = (const float*)d_in[0];
    float* out = (float*)d_out;

    const int M = 8192, N = 8192;
    const int Mb = M / TS, Nb = N / TS;      // 64 x 64 tiles
    float* out_q = out;                       // [M*N] quantized values (f32 transport)
    float* out_s = out + (size_t)M * N;       // [Mb*Nb] scales

    quantize_gm_kernel<<<dim3(Mb * Nb), dim3(THREADS), 0, stream>>>(x, out_q, out_s, Nb);
}

// Round 3
// 91.454 us; speedup vs baseline: 1.0767x; 1.0767x over previous
//
#include <hip/hip_runtime.h>
#include <stdint.h>

// Block-wise (128x128) fp8 e5m2 quantization with power-of-2 max-exponent scaling.
// Input:  x fp32 [8192, 8192]
// Output: d_out (f32 transport) = [8192*8192 quantized values] ++ [64*64 scales]
//
// One workgroup (512 threads) per 128x128 tile. Data held in registers
// (8 x float4 per thread) between the absmax pass and the quantize pass.
// R3: nontemporal loads/stores via clang ext_vector_type (HIP_vector_type
// is a struct and rejected by the builtin) — both streams are single-touch.

#define TS 128           // tile side
#define THREADS 512
#define NCOLS 8192
#define ROWS_PER_IT 16   // 512 threads / (128/4 float4 per row) = 16 rows per iteration
#define N_IT 8           // 128 rows / 16

typedef float f32x4 __attribute__((ext_vector_type(4)));

// Exact round-to-nearest-even f32 -> e5m2 -> f32 (value domain).
// |v| <= 4 after scaling (absmax normalized into [2,4)), so no saturation
// handling needed. Subnormal e5m2 (|v| < 2^-14) uses fixed quantum 2^-16.
__device__ __forceinline__ float quant_e5m2(float v) {
    uint32_t b = __float_as_uint(v);
    int e = (int)((b >> 23) & 0xFFu) - 127;        // unbiased exponent
    int ulp_e = (e >= -14) ? (e - 2) : -16;        // e5m2 ulp exponent
    float s  = __uint_as_float((uint32_t)(127 - ulp_e) << 23);  // 2^-ulp_e
    float si = __uint_as_float((uint32_t)(127 + ulp_e) << 23);  // 2^+ulp_e
    return rintf(v * s) * si;                      // v_rndne_f32: RNE, all steps exact
}

__global__ __launch_bounds__(THREADS) void quantize_gm_kernel(
    const float* __restrict__ x,
    float* __restrict__ out_q,
    float* __restrict__ out_s,
    int nb_cols)
{
    const int tile = blockIdx.x;
    const int tr = tile / nb_cols;
    const int tc = tile - tr * nb_cols;
    const size_t base = (size_t)tr * TS * NCOLS + (size_t)tc * TS;

    const int t = threadIdx.x;
    const int row0 = t >> 5;          // 0..15: row within the 16-row stripe
    const int c4 = (t & 31) << 2;     // float column within tile row: 0,4,...,124

    // ---- load tile into registers (coalesced nontemporal 16B) ----
    const f32x4* __restrict__ xin = reinterpret_cast<const f32x4*>(x + base + c4);
    f32x4 v[N_IT];
#pragma unroll
    for (int i = 0; i < N_IT; ++i) {
        size_t r4 = (size_t)(i * ROWS_PER_IT + row0) * (NCOLS / 4);
        v[i] = __builtin_nontemporal_load(xin + r4);
    }

    // ---- per-thread absmax ----
    float m = 0.0f;
#pragma unroll
    for (int i = 0; i < N_IT; ++i) {
        m = fmaxf(m, fmaxf(fmaxf(fabsf(v[i].x), fabsf(v[i].y)),
                           fmaxf(fabsf(v[i].z), fabsf(v[i].w))));
    }

    // ---- wave (64-lane) butterfly reduce ----
#pragma unroll
    for (int off = 32; off > 0; off >>= 1)
        m = fmaxf(m, __shfl_xor(m, off));

    // ---- cross-wave reduce via LDS ----
    __shared__ float smax[THREADS / 64];
    const int wave = t >> 6;
    if ((t & 63) == 0) smax[wave] = m;
    __syncthreads();
    float bm = smax[0];
#pragma unroll
    for (int w = 1; w < THREADS / 64; ++w) bm = fmaxf(bm, smax[w]);

    // ---- maxexp = floor(log2(absmax)) = exponent field (absmax normal, >0) ----
    const int maxexp = (int)((__float_as_uint(bm) >> 23) & 0xFFu) - 127;
    // factor = 2^(1 - maxexp): exact power of two.
    const float factor = __uint_as_float((uint32_t)(127 + 1 - maxexp) << 23);

    // ---- quantize + store (coalesced nontemporal 16B) ----
    float* __restrict__ oq = out_q + base + c4;
#pragma unroll
    for (int i = 0; i < N_IT; ++i) {
        size_t r = (size_t)(i * ROWS_PER_IT + row0) * NCOLS;
        f32x4 q;
        q.x = quant_e5m2(v[i].x * factor);
        q.y = quant_e5m2(v[i].y * factor);
        q.z = quant_e5m2(v[i].z * factor);
        q.w = quant_e5m2(v[i].w * factor);
        __builtin_nontemporal_store(q, reinterpret_cast<f32x4*>(oq + r));
    }

    if (t == 0)
        out_s[tile] = __uint_as_float((uint32_t)(127 + maxexp - 1) << 23);
}

extern "C" void kernel_launch(void* const* d_in, const int* in_sizes, int n_in,
                              void* d_out, int out_size, void* d_ws, size_t ws_size,
                              hipStream_t stream) {
    const float* x = (const float*)d_in[0];
    float* out = (float*)d_out;

    const int M = 8192, N = 8192;
    const int Mb = M / TS, Nb = N / TS;      // 64 x 64 tiles
    float* out_q = out;                       // [M*N] quantized values (f32 transport)
    float* out_s = out + (size_t)M * N;       // [Mb*Nb] scales

    quantize_gm_kernel<<<dim3(Mb * Nb), dim3(THREADS), 0, stream>>>(x, out_q, out_s, Nb);
}